// Round 1
// baseline (325.180 us; speedup 1.0000x reference)
//
#include <hip/hip_runtime.h>
#include <climits>

#define BQ    256      // batch rows (B)
#define DDIM  256      // feature dim (D)
#define NBANK 100000   // bank rows (N)
#define TN    64       // bank cols per block
#define BK    32       // k-slice
#define APAD  260      // 256 + 4 pad (keeps 16B alignment for b128 reads, breaks write conflicts)
#define BPAD  68       // 64 + 4 pad
#define NBLK  ((NBANK + TN - 1) / TN)   // 1563
#define SENT  1e30f    // "infinity" sentinel (real s values are O(1e3))

// Kernel 1: fused GEMM(score) + masked partial argmin.
// Each block: all 256 rows x 64 bank cols. score s_ij = ||b_j||^2 - 2<a_i,b_j>
// (same argmin as the reference's sqrt distance). ||b_j||^2 accumulated during
// B-tile staging. Writes per-(row,block) best {primary, diff-class} (val,idx).
__global__ __launch_bounds__(256) void gemm_argmin_partial(
    const float* __restrict__ feature,       // [256][256]
    const float* __restrict__ bank,          // [N][256]
    const int*   __restrict__ cluster_label, // [N]
    const int*   __restrict__ class_label,   // [N]
    const int*   __restrict__ cluster_idx,   // [256]
    const int*   __restrict__ gt_label,      // [256]
    float* __restrict__ wsPV, int* __restrict__ wsPI,
    float* __restrict__ wsDV, int* __restrict__ wsDI)
{
    __shared__ __align__(16) float smem[BK * APAD + BK * BPAD]; // 42 KB; reused for reduction
    float (*Al)[APAD] = (float(*)[APAD])smem;            // [k][row], transposed
    float (*Bl)[BPAD] = (float(*)[BPAD])(smem + BK * APAD); // [k][bankcol], transposed
    __shared__ float b2s[TN];
    __shared__ int   clsS[TN], cluS[TN];
    __shared__ int   rowClu[BQ], rowGt[BQ];
    __shared__ float sqpart[TN][4];

    const int tid = threadIdx.x;
    const int blk = blockIdx.x;
    const int j0  = blk * TN;

    if (tid < TN) {
        int jg = j0 + tid;
        int jc = jg < NBANK ? jg : NBANK - 1;
        clsS[tid] = class_label[jc];
        cluS[tid] = cluster_label[jc];
    }
    rowClu[tid] = cluster_idx[tid];
    rowGt[tid]  = gt_label[tid];

    float acc[8][8];
    #pragma unroll
    for (int i = 0; i < 8; ++i)
        #pragma unroll
        for (int j = 0; j < 8; ++j) acc[i][j] = 0.f;

    const int arow = tid >> 3;      // A staging: row within 32-row pass
    const int akq  = tid & 7;       // A staging: k-quad (float4)
    const int bj   = tid >> 2;      // B staging: bank col 0..63
    const int bkq  = tid & 3;       // B staging: covers k 8*bkq..+7
    const int ty   = tid >> 3;      // compute: row group (8 rows)
    const int tx   = tid & 7;       // compute: bank group (8 cols)
    const int jB   = j0 + bj;
    const int jBc  = jB < NBANK ? jB : NBANK - 1;
    float sqacc = 0.f;

    for (int kt = 0; kt < DDIM; kt += BK) {
        // Stage A tile [32][256] -> Al[k][row] (coalesced 128B-per-row-octet reads)
        #pragma unroll
        for (int p = 0; p < 8; ++p) {
            const int r = p * 32 + arow;
            const float4 v = *(const float4*)(feature + r * DDIM + kt + 4 * akq);
            Al[4 * akq + 0][r] = v.x; Al[4 * akq + 1][r] = v.y;
            Al[4 * akq + 2][r] = v.z; Al[4 * akq + 3][r] = v.w;
        }
        // Stage B tile [64][32] -> Bl[k][col]; accumulate ||b||^2 on the fly
        {
            const float4 u0 = *(const float4*)(bank + (size_t)jBc * DDIM + kt + 8 * bkq);
            const float4 u1 = *(const float4*)(bank + (size_t)jBc * DDIM + kt + 8 * bkq + 4);
            Bl[8 * bkq + 0][bj] = u0.x; Bl[8 * bkq + 1][bj] = u0.y;
            Bl[8 * bkq + 2][bj] = u0.z; Bl[8 * bkq + 3][bj] = u0.w;
            Bl[8 * bkq + 4][bj] = u1.x; Bl[8 * bkq + 5][bj] = u1.y;
            Bl[8 * bkq + 6][bj] = u1.z; Bl[8 * bkq + 7][bj] = u1.w;
            sqacc += u0.x * u0.x + u0.y * u0.y + u0.z * u0.z + u0.w * u0.w
                   + u1.x * u1.x + u1.y * u1.y + u1.z * u1.z + u1.w * u1.w;
        }
        __syncthreads();
        // 8x8 register micro-tile; fragment reads are ds_read_b128, <=2-way conflicts
        #pragma unroll 4
        for (int kk = 0; kk < BK; ++kk) {
            float a[8], bb[8];
            *(float4*)(a)      = *(const float4*)(&Al[kk][ty * 8]);
            *(float4*)(a + 4)  = *(const float4*)(&Al[kk][ty * 8 + 4]);
            *(float4*)(bb)     = *(const float4*)(&Bl[kk][tx * 8]);
            *(float4*)(bb + 4) = *(const float4*)(&Bl[kk][tx * 8 + 4]);
            #pragma unroll
            for (int i = 0; i < 8; ++i)
                #pragma unroll
                for (int j = 0; j < 8; ++j)
                    acc[i][j] = fmaf(a[i], bb[j], acc[i][j]);
        }
        __syncthreads();
    }

    // Reduce ||b_j||^2 partials (4 threads per bank col)
    sqpart[bj][bkq] = sqacc;
    __syncthreads();
    if (tid < TN)
        b2s[tid] = sqpart[tid][0] + sqpart[tid][1] + sqpart[tid][2] + sqpart[tid][3];
    __syncthreads();

    // Reuse tile LDS for per-(row, tx) argmin partials (A/B tiles are dead now)
    float* redPV = smem;
    int*   redPI = (int*)smem + 2048;
    float* redDV = smem + 4096;
    int*   redDI = (int*)smem + 6144;

    #pragma unroll
    for (int ri = 0; ri < 8; ++ri) {
        const int row = ty * 8 + ri;
        const int myClu = rowClu[row], myGt = rowGt[row];
        float bpv = SENT, bdv = SENT;
        int   bpi = INT_MAX, bdi = INT_MAX;
        #pragma unroll
        for (int jj = 0; jj < 8; ++jj) {   // ascending j => strict '<' keeps lowest index
            const int jl = tx * 8 + jj;
            const int jg = j0 + jl;
            if (jg < NBANK) {
                const float s = b2s[jl] - 2.f * acc[ri][jj];
                if (clsS[jl] != myGt) {
                    if (s < bdv) { bdv = s; bdi = jg; }
                    if (cluS[jl] == myClu && s < bpv) { bpv = s; bpi = jg; }
                }
            }
        }
        redPV[row * 8 + tx] = bpv; redPI[row * 8 + tx] = bpi;
        redDV[row * 8 + tx] = bdv; redDI[row * 8 + tx] = bdi;
    }
    __syncthreads();

    // Per-row combine across the 8 tx groups; write partials (row-major for coalesced k2 reads)
    {
        const int row = tid;
        float bpv = SENT, bdv = SENT;
        int   bpi = INT_MAX, bdi = INT_MAX;
        #pragma unroll
        for (int t = 0; t < 8; ++t) {
            float v = redPV[row * 8 + t]; int ix = redPI[row * 8 + t];
            if (v < bpv || (v == bpv && ix < bpi)) { bpv = v; bpi = ix; }
            v = redDV[row * 8 + t]; ix = redDI[row * 8 + t];
            if (v < bdv || (v == bdv && ix < bdi)) { bdv = v; bdi = ix; }
        }
        wsPV[(size_t)row * NBLK + blk] = bpv; wsPI[(size_t)row * NBLK + blk] = bpi;
        wsDV[(size_t)row * NBLK + blk] = bdv; wsDI[(size_t)row * NBLK + blk] = bdi;
    }
}

// Kernel 2: per-row reduction over NBLK partials, fallback select, gather bank row.
__global__ __launch_bounds__(256) void reduce_gather(
    const float* __restrict__ wsPV, const int* __restrict__ wsPI,
    const float* __restrict__ wsDV, const int* __restrict__ wsDI,
    const float* __restrict__ bank, float* __restrict__ out)
{
    const int row = blockIdx.x, tid = threadIdx.x;
    float bpv = SENT, bdv = SENT;
    int   bpi = INT_MAX, bdi = INT_MAX;
    for (int b = tid; b < NBLK; b += 256) {
        float v = wsPV[(size_t)row * NBLK + b]; int ix = wsPI[(size_t)row * NBLK + b];
        if (v < bpv || (v == bpv && ix < bpi)) { bpv = v; bpi = ix; }
        v = wsDV[(size_t)row * NBLK + b]; ix = wsDI[(size_t)row * NBLK + b];
        if (v < bdv || (v == bdv && ix < bdi)) { bdv = v; bdi = ix; }
    }
    // wave-64 shuffle reduction (index tiebreak keeps argmin-first semantics)
    #pragma unroll
    for (int off = 32; off > 0; off >>= 1) {
        float v = __shfl_down(bpv, off); int ix = __shfl_down(bpi, off);
        if (v < bpv || (v == bpv && ix < bpi)) { bpv = v; bpi = ix; }
        v = __shfl_down(bdv, off); ix = __shfl_down(bdi, off);
        if (v < bdv || (v == bdv && ix < bdi)) { bdv = v; bdi = ix; }
    }
    __shared__ float swPV[4], swDV[4];
    __shared__ int   swPI[4], swDI[4];
    __shared__ int   sIdx;
    const int lane = tid & 63, wv = tid >> 6;
    if (lane == 0) { swPV[wv] = bpv; swPI[wv] = bpi; swDV[wv] = bdv; swDI[wv] = bdi; }
    __syncthreads();
    if (tid == 0) {
        float pv = swPV[0]; int pi = swPI[0];
        float dv = swDV[0]; int di = swDI[0];
        #pragma unroll
        for (int w = 1; w < 4; ++w) {
            if (swPV[w] < pv || (swPV[w] == pv && swPI[w] < pi)) { pv = swPV[w]; pi = swPI[w]; }
            if (swDV[w] < dv || (swDV[w] == dv && swDI[w] < di)) { dv = swDV[w]; di = swDI[w]; }
        }
        sIdx = (pi != INT_MAX) ? pi : ((di != INT_MAX) ? di : 0);
    }
    __syncthreads();
    out[row * DDIM + tid] = bank[(size_t)sIdx * DDIM + tid];
}

extern "C" void kernel_launch(void* const* d_in, const int* in_sizes, int n_in,
                              void* d_out, int out_size, void* d_ws, size_t ws_size,
                              hipStream_t stream) {
    const float* feature       = (const float*)d_in[0];
    const float* bank          = (const float*)d_in[1];
    const int*   cluster_label = (const int*)d_in[2];
    const int*   class_label   = (const int*)d_in[3];
    const int*   cluster_idx   = (const int*)d_in[4];
    const int*   gt_label      = (const int*)d_in[5];
    float* out = (float*)d_out;

    // Workspace: 4 arrays of [256][NBLK] (val/idx for primary & diff) = 6.4 MB
    const size_t per = (size_t)BQ * NBLK;
    float* wsPV = (float*)d_ws;
    int*   wsPI = (int*)d_ws + per;
    float* wsDV = (float*)d_ws + 2 * per;
    int*   wsDI = (int*)d_ws + 3 * per;

    hipLaunchKernelGGL(gemm_argmin_partial, dim3(NBLK), dim3(256), 0, stream,
                       feature, bank, cluster_label, class_label, cluster_idx, gt_label,
                       wsPV, wsPI, wsDV, wsDI);
    hipLaunchKernelGGL(reduce_gather, dim3(BQ), dim3(256), 0, stream,
                       wsPV, wsPI, wsDV, wsDI, bank, out);
}

// Round 2
// 319.724 us; speedup vs baseline: 1.0171x; 1.0171x over previous
//
#include <hip/hip_runtime.h>
#include <climits>

#define BQ    256      // batch rows (B)
#define DDIM  256      // feature dim (D)
#define NBANK 100000   // bank rows (N)
#define BM    128      // batch rows per block
#define BN    128      // bank cols per block
#define BK    32       // k-slice
#define NJB   ((NBANK + BN - 1) / BN)   // 782
#define RED_S 17       // padded stride for epilogue reduction arrays
#define SENT  1e30f

// Kernel 1: fused GEMM(score) + masked partial argmin, swizzled LDS (conflict-free).
// score s_ij = ||b_j||^2 - 2<a_i,b_j> (argmin-equivalent to the reference's sqrt dist).
__global__ __launch_bounds__(256, 3) void gemm_argmin_partial(
    const float* __restrict__ feature,       // [256][256]
    const float* __restrict__ bank,          // [N][256]
    const int*   __restrict__ cluster_label, // [N]
    const int*   __restrict__ class_label,   // [N]
    const int*   __restrict__ cluster_idx,   // [256]
    const int*   __restrict__ gt_label,      // [256]
    float* __restrict__ wsPV, int* __restrict__ wsPI,
    float* __restrict__ wsDV, int* __restrict__ wsDI)
{
    // 8704 floats: tiles use [0,8192) (Al 4096 | Bl 4096); epilogue overlays 4x(128*17)
    __shared__ __align__(16) float smem[8704];
    __shared__ float b2s[BN];
    __shared__ int   clsS[BN], cluS[BN], rowClu[BM], rowGt[BM];

    float* Al = smem;            // [BK][BM], col-swizzled
    float* Bl = smem + BK * BM;  // [BK][BN], col-swizzled

    const int tid  = threadIdx.x;
    const int jb   = blockIdx.x;           // j-block (0..781)
    const int row0 = blockIdx.y * BM;      // row half (0 or 128)
    const int j0   = jb * BN;

    if (tid < BN) {
        int jg = j0 + tid;
        int jc = jg < NBANK ? jg : NBANK - 1;
        clsS[tid] = class_label[jc];
        cluS[tid] = cluster_label[jc];
    }
    if (tid < BM) {
        rowClu[tid] = cluster_idx[row0 + tid];
        rowGt[tid]  = gt_label[row0 + tid];
    }

    const int r  = tid >> 3;        // staging row/col base (0..31), +32*p
    const int q  = tid & 7;         // staging k-chunk (float4)
    const int ty = tid >> 4;        // compute: row group (8 rows)
    const int tx = tid & 15;        // compute: col group (8 cols)
    const int physc = (q & 3) << 3; // write-side swizzle

    const float* gA[4];
    const float* gB[4];
    #pragma unroll
    for (int p = 0; p < 4; ++p) {
        const int rr = r + 32 * p;
        gA[p] = feature + (size_t)(row0 + rr) * DDIM + 4 * q;
        const int j  = j0 + rr;
        const int jc = j < NBANK ? j : NBANK - 1;
        gB[p] = bank + (size_t)jc * DDIM + 4 * q;
    }

    float acc[8][8] = {};
    float sqa[4] = {0.f, 0.f, 0.f, 0.f};

    for (int kt = 0; kt < DDIM; kt += BK) {
        float4 va[4], vb[4];
        #pragma unroll
        for (int p = 0; p < 4; ++p) {
            va[p] = *(const float4*)(gA[p] + kt);
            vb[p] = *(const float4*)(gB[p] + kt);
        }
        __syncthreads();   // previous compute done before overwriting tiles
        #pragma unroll
        for (int p = 0; p < 4; ++p) {
            const int pr = (r + 32 * p) ^ physc;
            const int k0 = 4 * q;
            Al[(k0 + 0) * BM + pr] = va[p].x; Al[(k0 + 1) * BM + pr] = va[p].y;
            Al[(k0 + 2) * BM + pr] = va[p].z; Al[(k0 + 3) * BM + pr] = va[p].w;
            Bl[(k0 + 0) * BN + pr] = vb[p].x; Bl[(k0 + 1) * BN + pr] = vb[p].y;
            Bl[(k0 + 2) * BN + pr] = vb[p].z; Bl[(k0 + 3) * BN + pr] = vb[p].w;
            sqa[p] = fmaf(vb[p].x, vb[p].x, fmaf(vb[p].y, vb[p].y,
                     fmaf(vb[p].z, vb[p].z, fmaf(vb[p].w, vb[p].w, sqa[p]))));
        }
        __syncthreads();
        #pragma unroll 4
        for (int kk = 0; kk < BK; ++kk) {
            const int swz = (kk & 12) << 1;          // read-side swizzle (== write side)
            const float4* pa = (const float4*)(Al + kk * BM + ((ty * 8) ^ swz));
            const float4* pb = (const float4*)(Bl + kk * BN + ((tx * 8) ^ swz));
            float a[8], bb[8];
            *(float4*)(a)      = pa[0]; *(float4*)(a + 4)  = pa[1];
            *(float4*)(bb)     = pb[0]; *(float4*)(bb + 4) = pb[1];
            #pragma unroll
            for (int i = 0; i < 8; ++i)
                #pragma unroll
                for (int j = 0; j < 8; ++j)
                    acc[i][j] = fmaf(a[i], bb[j], acc[i][j]);
        }
    }

    // ||b_j||^2: 8 staging threads per col are adjacent lanes -> shfl butterfly
    #pragma unroll
    for (int p = 0; p < 4; ++p) {
        float v = sqa[p];
        v += __shfl_xor(v, 1);
        v += __shfl_xor(v, 2);
        v += __shfl_xor(v, 4);
        if (q == 0) b2s[r + 32 * p] = v;
    }
    __syncthreads();   // b2s ready; tiles dead -> overlay reduction arrays

    float* redPV = smem;
    int*   redPI = (int*)(smem + 2176);
    float* redDV = smem + 4352;
    int*   redDI = (int*)(smem + 6528);

    #pragma unroll
    for (int ri = 0; ri < 8; ++ri) {
        const int row = ty * 8 + ri;
        const int myClu = rowClu[row], myGt = rowGt[row];
        float bpv = SENT, bdv = SENT;
        int   bpi = INT_MAX, bdi = INT_MAX;
        #pragma unroll
        for (int jj = 0; jj < 8; ++jj) {   // ascending j + strict '<' => lowest index
            const int jl = tx * 8 + jj;
            const int jg = j0 + jl;
            if (jg < NBANK) {
                const float s = b2s[jl] - 2.f * acc[ri][jj];
                if (clsS[jl] != myGt) {
                    if (s < bdv) { bdv = s; bdi = jg; }
                    if (cluS[jl] == myClu && s < bpv) { bpv = s; bpi = jg; }
                }
            }
        }
        redPV[row * RED_S + tx] = bpv; redPI[row * RED_S + tx] = bpi;
        redDV[row * RED_S + tx] = bdv; redDI[row * RED_S + tx] = bdi;
    }
    __syncthreads();

    if (tid < BM) {
        const int row = tid;
        float bpv = SENT, bdv = SENT;
        int   bpi = INT_MAX, bdi = INT_MAX;
        #pragma unroll
        for (int t = 0; t < 16; ++t) {
            float v = redPV[row * RED_S + t]; int ix = redPI[row * RED_S + t];
            if (v < bpv || (v == bpv && ix < bpi)) { bpv = v; bpi = ix; }
            v = redDV[row * RED_S + t]; ix = redDI[row * RED_S + t];
            if (v < bdv || (v == bdv && ix < bdi)) { bdv = v; bdi = ix; }
        }
        const size_t o = (size_t)(row0 + row) * NJB + jb;
        wsPV[o] = bpv; wsPI[o] = bpi;
        wsDV[o] = bdv; wsDI[o] = bdi;
    }
}

// Kernel 2: per-row reduction over NJB partials, fallback select, gather bank row.
__global__ __launch_bounds__(256) void reduce_gather(
    const float* __restrict__ wsPV, const int* __restrict__ wsPI,
    const float* __restrict__ wsDV, const int* __restrict__ wsDI,
    const float* __restrict__ bank, float* __restrict__ out)
{
    const int row = blockIdx.x, tid = threadIdx.x;
    float bpv = SENT, bdv = SENT;
    int   bpi = INT_MAX, bdi = INT_MAX;
    for (int b = tid; b < NJB; b += 256) {
        float v = wsPV[(size_t)row * NJB + b]; int ix = wsPI[(size_t)row * NJB + b];
        if (v < bpv || (v == bpv && ix < bpi)) { bpv = v; bpi = ix; }
        v = wsDV[(size_t)row * NJB + b]; ix = wsDI[(size_t)row * NJB + b];
        if (v < bdv || (v == bdv && ix < bdi)) { bdv = v; bdi = ix; }
    }
    #pragma unroll
    for (int off = 32; off > 0; off >>= 1) {
        float v = __shfl_down(bpv, off); int ix = __shfl_down(bpi, off);
        if (v < bpv || (v == bpv && ix < bpi)) { bpv = v; bpi = ix; }
        v = __shfl_down(bdv, off); ix = __shfl_down(bdi, off);
        if (v < bdv || (v == bdv && ix < bdi)) { bdv = v; bdi = ix; }
    }
    __shared__ float swPV[4], swDV[4];
    __shared__ int   swPI[4], swDI[4];
    __shared__ int   sIdx;
    const int lane = tid & 63, wv = tid >> 6;
    if (lane == 0) { swPV[wv] = bpv; swPI[wv] = bpi; swDV[wv] = bdv; swDI[wv] = bdi; }
    __syncthreads();
    if (tid == 0) {
        float pv = swPV[0]; int pi = swPI[0];
        float dv = swDV[0]; int di = swDI[0];
        #pragma unroll
        for (int w = 1; w < 4; ++w) {
            if (swPV[w] < pv || (swPV[w] == pv && swPI[w] < pi)) { pv = swPV[w]; pi = swPI[w]; }
            if (swDV[w] < dv || (swDV[w] == dv && swDI[w] < di)) { dv = swDV[w]; di = swDI[w]; }
        }
        sIdx = (pi != INT_MAX) ? pi : ((di != INT_MAX) ? di : 0);
    }
    __syncthreads();
    out[row * DDIM + tid] = bank[(size_t)sIdx * DDIM + tid];
}

extern "C" void kernel_launch(void* const* d_in, const int* in_sizes, int n_in,
                              void* d_out, int out_size, void* d_ws, size_t ws_size,
                              hipStream_t stream) {
    const float* feature       = (const float*)d_in[0];
    const float* bank          = (const float*)d_in[1];
    const int*   cluster_label = (const int*)d_in[2];
    const int*   class_label   = (const int*)d_in[3];
    const int*   cluster_idx   = (const int*)d_in[4];
    const int*   gt_label      = (const int*)d_in[5];
    float* out = (float*)d_out;

    // Workspace: 4 arrays of [256][NJB] = 3.2 MB
    const size_t per = (size_t)BQ * NJB;
    float* wsPV = (float*)d_ws;
    int*   wsPI = (int*)d_ws + per;
    float* wsDV = (float*)d_ws + 2 * per;
    int*   wsDI = (int*)d_ws + 3 * per;

    hipLaunchKernelGGL(gemm_argmin_partial, dim3(NJB, 2), dim3(256), 0, stream,
                       feature, bank, cluster_label, class_label, cluster_idx, gt_label,
                       wsPV, wsPI, wsDV, wsDI);
    hipLaunchKernelGGL(reduce_gather, dim3(BQ), dim3(256), 0, stream,
                       wsPV, wsPI, wsDV, wsDI, bank, out);
}